// Round 6
// baseline (153.754 us; speedup 1.0000x reference)
//
#include <hip/hip_runtime.h>
#include <hip/hip_bf16.h>
#include <cstddef>

typedef __hip_bfloat16 bf16;

#define SB   2048  // scan blocks (block-local lists, no global-zero dependency)
#define WB   64    // cache-warm blocks prepended to k_scan's grid
#define SL   32    // per-scan-block src slot capacity (expected ~0.016 hits/block)
#define CAP  256   // compact list capacity (expected ~32 total, >20 sigma)
#define TILE 64    // nodes staged in LDS per gather tile

__device__ __forceinline__ float ldf(const void* p, int isf32, long long i) {
    if (isf32) return ((const float*)p)[i];
    return __bfloat162float(((const bf16*)p)[i]);
}

// per-wave dtype/width detection (~80 L1-hit loads + 2 ballots)
__device__ __forceinline__ void detect(const void* ei, const void* wenc,
                                       int& is64, int& isf32) {
    int l = threadIdx.x & 63;
    int hi = (l < 16) ? ((const int*)ei)[2 * l + 1] : 0;   // int64 => high words 0
    unsigned long long any_hi = __ballot(hi != 0);
    unsigned short u = ((const unsigned short*)wenc)[l];   // fp32 halves: random
    unsigned short ex = (u >> 7) & 0xFF;
    unsigned long long any_big = __ballot(ex >= 137);
    is64  = (any_hi == 0ull) ? 1 : 0;
    isf32 = (any_big != 0ull) ? 1 : 0;
}

// Rebuild the compact (src, slot) list from cnts/srcs. Entries carry their
// global slot id so the (nondeterministic) list ORDER never matters.
__device__ __forceinline__ void build_list(const int* __restrict__ cnts,
                                           const int* __restrict__ srcs,
                                           int* ls_src, int* ls_slot,
                                           int* sh_cnt, int* sh_tot,
                                           int& cnt, int& tot) {
    const int t = threadIdx.x;
    if (t == 0) { *sh_cnt = 0; *sh_tot = 0; }
    __syncthreads();
    for (int i = t; i < SB; i += 256) {
        int c = cnts[i];
        if (c > 0) {
            atomicAdd(sh_tot, c);                  // true total (deg of node 0)
            int cc = min(c, SL);
            int base = atomicAdd(sh_cnt, cc);
            for (int j = 0; j < cc; j++) {
                int pos = base + j;
                if (pos < CAP) {
                    ls_src[pos]  = srcs[i * SL + j];
                    ls_slot[pos] = i * SL + j;
                }
            }
        }
    }
    __syncthreads();
    cnt = min(*sh_cnt, CAP);
    tot = *sh_tot;
}

// ---- D1: blocks [0,WB): stream all GRU/GCN weights into L2/L3 (cache warm
//          for k_gru, overlapped with the scan). blocks [WB, WB+SB): grid-
//          stride dst scan -> LDS-local dst==0 list, flush to cnts/srcs
//          (unconditional writes: NO memset needed), zero own degs slice. ----
__global__ void __launch_bounds__(256) k_scan(
        const void* __restrict__ ei, long long E,
        const void* __restrict__ Wenc,           // + dtype detect
        const void* __restrict__ Wgcn,
        const void* __restrict__ Wih, const void* __restrict__ Whh,
        int* __restrict__ cnts, int* __restrict__ srcs,
        int* __restrict__ degs) {
    __shared__ int lc;
    __shared__ int ls[SL];
    int is64, isf32;
    detect(ei, Wenc, is64, isf32);
    const int b = blockIdx.x;
    const int t = threadIdx.x;
    if (b < WB) {
        // warm Wenc/Wgcn/Wih/Whh (~1.25 MB fp32) into L2/L3
        const long long esz = isf32 ? 4 : 2;
        const void* arrs[4]  = { Wenc, Wgcn, Wih, Whh };
        const long long el[4] = { 128 * 64, 128 * 128, 768 * 128, 768 * 256 };
        int acc = 0;
        for (int a = 0; a < 4; a++) {
            const char* pb = (const char*)arrs[a];
            const long long nb = el[a] * esz;
            for (long long off = ((long long)b * 256 + t) * 16;
                 off + 16 <= nb; off += (long long)WB * 256 * 16) {
                int4 v = *(const int4*)(pb + off);
                acc += v.x + v.y + v.z + v.w;
            }
        }
        asm volatile("" :: "v"(acc));              // keep loads alive
        return;
    }
    const int sb = b - WB;                         // 0..SB-1
    if (t == 0) lc = 0;
    if (t < SL) degs[sb * SL + t] = 0;             // zero my degs slice
    __syncthreads();
    const long long NT = (long long)SB * 256;
    if ((E & 1) == 0) {
        const long long P = E >> 1;
        for (long long p = (long long)sb * 256 + t; p < P; p += NT) {
            int d0, d1;
            if (is64) {
                longlong2 dd = ((const longlong2*)ei)[P + p];
                d0 = (int)dd.x; d1 = (int)dd.y;
            } else {
                int2 dd = ((const int2*)ei)[P + p];
                d0 = dd.x; d1 = dd.y;
            }
            if (d0 == 0) {
                int q = atomicAdd(&lc, 1);
                if (q < SL) ls[q] = (int)(is64 ? ((const long long*)ei)[2*p]
                                               : (long long)((const int*)ei)[2*p]);
            }
            if (d1 == 0) {
                int q = atomicAdd(&lc, 1);
                if (q < SL) ls[q] = (int)(is64 ? ((const long long*)ei)[2*p+1]
                                               : (long long)((const int*)ei)[2*p+1]);
            }
        }
    } else {
        for (long long e = (long long)sb * 256 + t; e < E; e += NT) {
            int d = is64 ? (int)((const long long*)ei)[E + e] : ((const int*)ei)[E + e];
            if (d == 0) {
                int q = atomicAdd(&lc, 1);
                if (q < SL) ls[q] = (int)(is64 ? ((const long long*)ei)[e]
                                               : (long long)((const int*)ei)[e]);
            }
        }
    }
    __syncthreads();
    int c = lc;
    if (t == 0) cnts[sb] = c;                      // unconditional: no zero-init
    if (t < min(c, SL)) srcs[sb * SL + t] = ls[t];
}

// ---- D2: in-degree of listed srcs: rebuild list, grid-stride dst scan,
//          atomics only on hits (~2K total). Block DB prefetches the listed
//          nf rows into L2/L3 for k_gru. ----
__global__ void __launch_bounds__(256) k_deg(
        const void* __restrict__ ei, long long E,
        const void* __restrict__ wenc,           // dtype detect only
        const void* __restrict__ nf,
        const int* __restrict__ cnts, const int* __restrict__ srcs,
        int* __restrict__ degs, int DB) {
    __shared__ int ls_src[CAP];
    __shared__ int ls_slot[CAP];
    __shared__ int sh_cnt, sh_tot;
    int is64, isf32;
    detect(ei, wenc, is64, isf32);
    int cnt, tot;
    build_list(cnts, srcs, ls_src, ls_slot, &sh_cnt, &sh_tot, cnt, tot);
    const int b = blockIdx.x;
    const int t = threadIdx.x;
    if (b >= DB) {                                 // prefetch block
        float s = 0.0f;
        for (int idx = t; idx < cnt * 64; idx += 256)
            s += ldf(nf, isf32, (long long)ls_src[idx >> 6] * 64 + (idx & 63));
        asm volatile("" :: "v"(s));
        return;
    }
    const long long NT = (long long)DB * 256;
    if ((E & 1) == 0) {
        const long long P = E >> 1;
        for (long long p = (long long)b * 256 + t; p < P; p += NT) {
            int d0, d1;
            if (is64) {
                longlong2 dd = ((const longlong2*)ei)[P + p];
                d0 = (int)dd.x; d1 = (int)dd.y;
            } else {
                int2 dd = ((const int2*)ei)[P + p];
                d0 = dd.x; d1 = dd.y;
            }
            for (int j = 0; j < cnt; j++) {
                if (ls_src[j] == d0) atomicAdd(&degs[ls_slot[j]], 1);
                if (ls_src[j] == d1) atomicAdd(&degs[ls_slot[j]], 1);
            }
        }
    } else {
        for (long long e = (long long)b * 256 + t; e < E; e += NT) {
            int d = is64 ? (int)((const long long*)ei)[E + e] : ((const int*)ei)[E + e];
            for (int j = 0; j < cnt; j++)
                if (ls_src[j] == d) atomicAdd(&degs[ls_slot[j]], 1);
        }
    }
}

// ---- D3: 256 blocks; each block computes the gather ONCE as a batched
//      matmul: ysum = sum_i norm_i * relu(Wenc x_i + benc)  (tile in LDS,
//      Wenc row cached in regs), then ONE Wgcn matvec (linearity), then its
//      own output out[b] — including the gh rows {b,256+b,512+b} of
//      Whh.hid+bhh computed locally (gh producer kernel eliminated). ----
__global__ void __launch_bounds__(256) k_gru(
        const void* __restrict__ ei,             // dtype detect only
        const void* __restrict__ nf,
        const void* __restrict__ Wenc, const void* __restrict__ benc,
        const void* __restrict__ Wgcn, const void* __restrict__ bgcn,
        const void* __restrict__ hid,
        const void* __restrict__ Wih,  const void* __restrict__ bih,
        const void* __restrict__ Whh,  const void* __restrict__ bhh,
        const int* __restrict__ cnts, const int* __restrict__ srcs,
        const int* __restrict__ degs, void* __restrict__ out) {
    __shared__ int   ls_src[CAP];
    __shared__ int   ls_slot[CAP];
    __shared__ int   sh_cnt, sh_tot;
    __shared__ float norm_s[CAP + 1];
    __shared__ float hid_s[256];
    __shared__ __align__(16) float xs[TILE][64];
    __shared__ float part[2][128];
    __shared__ float ysum_s[128];
    __shared__ float g0_s[128];
    __shared__ float red_ih[3], red_hh[3];
    int is64, isf32;
    detect(ei, Wenc, is64, isf32);
    (void)is64;
    int cnt, tot;
    build_list(cnts, srcs, ls_src, ls_slot, &sh_cnt, &sh_tot, cnt, tot);
    const int t = threadIdx.x;
    const int lane = t & 63, wid = t >> 6;
    const int td = t & 127, hf = t >> 7;           // dim 0..127, node-parity
    hid_s[t] = ldf(hid, isf32, t);

    // per-entry norms (duplicate srcs each carry their own slot: correct)
    const int deg0 = tot + 1;                      // + self loop
    const float r0 = rsqrtf((float)deg0);
    for (int i = t; i < cnt; i += 256)
        norm_s[i] = rsqrtf((float)(degs[ls_slot[i]] + 1)) * r0;
    if (t == 0) norm_s[cnt] = 1.0f / (float)deg0;  // self loop (0,0)
    const int total = cnt + 1;

    // cache Wenc row td in registers (f32 path)
    float4 wreg[16];
    if (isf32) {
        const float4* wr = (const float4*)((const float*)Wenc + (size_t)td * 64);
        #pragma unroll
        for (int k = 0; k < 16; k++) wreg[k] = wr[k];
    }
    const float be = ldf(benc, isf32, td);
    float ysum_acc = 0.0f;
    __syncthreads();

    for (int base = 0; base < total; base += TILE) {
        const int tn = min(TILE, total - base);
        // stage node rows for this tile
        for (int idx = t; idx < tn * 64; idx += 256) {
            int j = idx >> 6, c = idx & 63;
            int node = base + j;
            int s = (node < cnt) ? ls_src[node] : 0;
            xs[j][c] = ldf(nf, isf32, (long long)s * 64 + c);
        }
        __syncthreads();
        if (isf32) {
            for (int jj = hf; jj < tn; jj += 4) {  // nodes jj, jj+2 (2-way ILP)
                const int ok2 = (jj + 2 < tn);
                const float4* xa = (const float4*)xs[jj];
                const float4* xb = (const float4*)xs[ok2 ? jj + 2 : jj];
                float aa = 0.0f, ab = 0.0f;
                #pragma unroll
                for (int k = 0; k < 16; k++) {
                    float4 va = xa[k], vb = xb[k], w = wreg[k];
                    aa += w.x*va.x + w.y*va.y + w.z*va.z + w.w*va.w;
                    ab += w.x*vb.x + w.y*vb.y + w.z*vb.z + w.w*vb.w;
                }
                float ya = fmaxf(aa + be, 0.0f);
                float yb = fmaxf(ab + be, 0.0f);
                ysum_acc += norm_s[base + jj] * ya
                          + (ok2 ? norm_s[base + jj + 2] * yb : 0.0f);
            }
        } else {
            for (int j = hf; j < tn; j += 2) {
                float acc = 0.0f;
                for (int k = 0; k < 64; k++)
                    acc += ldf(Wenc, 0, (long long)td * 64 + k) * xs[j][k];
                ysum_acc += norm_s[base + j] * fmaxf(acc + be, 0.0f);
            }
        }
        __syncthreads();                           // xs reused next tile
    }
    part[hf][td] = ysum_acc;
    __syncthreads();
    if (t < 128) ysum_s[t] = part[0][t] + part[1][t];
    __syncthreads();

    // single Wgcn matvec: thread (td,hf) does half-row td, k in [hf*64, hf*64+64)
    {
        float acc = 0.0f;
        if (isf32) {
            const float4* gr = (const float4*)((const float*)Wgcn
                                + (size_t)td * 128 + (size_t)hf * 64);
            const float* ys = ysum_s + hf * 64;
            #pragma unroll
            for (int k = 0; k < 16; k++) {
                float4 v = gr[k];
                acc += v.x*ys[4*k] + v.y*ys[4*k+1] + v.z*ys[4*k+2] + v.w*ys[4*k+3];
            }
        } else {
            for (int k = 0; k < 64; k++)
                acc += ldf(Wgcn, 0, (long long)td * 128 + hf * 64 + k)
                     * ysum_s[hf * 64 + k];
        }
        part[hf][td] = acc;
    }
    __syncthreads();
    if (t < 128)
        g0_s[t] = fmaxf(part[0][t] + part[1][t] + ldf(bgcn, isf32, t), 0.0f);
    __syncthreads();

    // GRU for output element b: wave p computes gi row p*256+b (Wih . g0)
    // AND gh row p*256+b (Whh . hid) — gh producer kernel eliminated.
    const int b = blockIdx.x;
    if (wid < 3) {
        long long j = (long long)wid * 256 + b;
        float aih, ahh = 0.0f;
        if (isf32) {
            const float* wr = (const float*)Wih + (size_t)j * 128;
            aih = wr[lane] * g0_s[lane] + wr[64 + lane] * g0_s[64 + lane];
            const float* hr = (const float*)Whh + (size_t)j * 256;
            #pragma unroll
            for (int q = 0; q < 4; q++)
                ahh += hr[q * 64 + lane] * hid_s[q * 64 + lane];
        } else {
            aih = ldf(Wih, 0, j * 128 + lane)      * g0_s[lane]
                + ldf(Wih, 0, j * 128 + 64 + lane) * g0_s[64 + lane];
            #pragma unroll
            for (int q = 0; q < 4; q++)
                ahh += ldf(Whh, 0, j * 256 + q * 64 + lane) * hid_s[q * 64 + lane];
        }
        #pragma unroll
        for (int off = 32; off > 0; off >>= 1) {
            aih += __shfl_down(aih, off);
            ahh += __shfl_down(ahh, off);
        }
        if (lane == 0) { red_ih[wid] = aih; red_hh[wid] = ahh; }
    }
    __syncthreads();
    if (t == 0) {
        float gh0 = red_hh[0] + ldf(bhh, isf32, b);
        float gh1 = red_hh[1] + ldf(bhh, isf32, 256 + b);
        float gh2 = red_hh[2] + ldf(bhh, isf32, 512 + b);
        float rr = 1.0f / (1.0f + expf(-(red_ih[0] + ldf(bih, isf32, b)       + gh0)));
        float zz = 1.0f / (1.0f + expf(-(red_ih[1] + ldf(bih, isf32, 256 + b) + gh1)));
        float nn = tanhf(red_ih[2] + ldf(bih, isf32, 512 + b) + rr * gh2);
        float hh = hid_s[b];
        float val = (1.0f - zz) * nn + zz * hh;
        if (isf32) ((float*)out)[b] = val;
        else       ((bf16*)out)[b]  = __float2bfloat16(val);
    }
}

extern "C" void kernel_launch(void* const* d_in, const int* in_sizes, int n_in,
                              void* d_out, int out_size, void* d_ws, size_t ws_size,
                              hipStream_t stream) {
    const void* nf   = d_in[0];
    // d_in[1] edge_attr: unused by the reference
    const void* hid  = d_in[2];
    const void* Wenc = d_in[3];
    const void* benc = d_in[4];
    const void* Wgcn = d_in[5];
    const void* bgcn = d_in[6];
    const void* Wih  = d_in[7];
    const void* Whh  = d_in[8];
    const void* bih  = d_in[9];
    const void* bhh  = d_in[10];
    const void* ei   = d_in[11];
    long long E = in_sizes[11] / 2;      // edge count (in_sizes = element counts)

    // workspace: [cnts SB][srcs SB*SL][degs SB*SL] ≈ 532 KB.
    // NOTHING here needs host-side zeroing (cnts written unconditionally;
    // degs zeroed inside k_scan; srcs only read where written).
    int* cnts = (int*)d_ws;
    int* srcs = cnts + SB;
    int* degs = srcs + SB * SL;

    const int DB = 2048;
    k_scan<<<WB + SB, 256, 0, stream>>>(ei, E, Wenc, Wgcn, Wih, Whh,
                                        cnts, srcs, degs);
    k_deg<<<DB + 1, 256, 0, stream>>>(ei, E, Wenc, nf, cnts, srcs, degs, DB);
    k_gru<<<256, 256, 0, stream>>>(ei, nf, Wenc, benc, Wgcn, bgcn, hid,
                                   Wih, bih, Whh, bhh, cnts, srcs, degs, d_out);
}